// Round 5
// baseline (250.078 us; speedup 1.0000x reference)
//
#include <hip/hip_runtime.h>

// dense_image_warp: B=8, H=512, W=512, C=16, fp32.
//
// R4: 4x thread coarsening for memory-level parallelism.
// Evidence: R0 (row blocks), R1/R3 (nt-store, 2D tiles + XCD swizzle) all land
// at 81 us with HBM 32%, VALU 12%, LDS 0, occupancy 75% -- locality-insensitive,
// nothing saturated => VMEM-latency-bound (serial flow->gather chain per thread,
// ~2 latency epochs per pixel-unit, waves mostly parked on vmcnt).
// Fix: each thread handles 4 float4-units (grid-stride chunks of 2M units):
//   phase 1: 4 independent flow loads        (was 1)
//   phase 2: all address math
//   phase 3: 16 independent corner gathers   (was 4)
//   phase 4: interpolate + 4 coalesced stores
// Flow latency amortized 4x; outstanding gathers per wave 4x.
//
// unit u = (pix<<2)|cg, pix = (b*512+y)*512+x. Lanes 4p..4p+3 cover one
// pixel's 4 channel groups -> every gather is a 64B contiguous segment,
// stores are 16B/lane fully coalesced.

#define NPIX 4
#define CHUNK (8 * 512 * 512 * 4 / NPIX)   // 2097152 units per chunk

__global__ __launch_bounds__(256) void warp_kernel(
    const float* __restrict__ img,
    const float* __restrict__ flow,
    float* __restrict__ out)
{
    const int t0 = blockIdx.x * blockDim.x + threadIdx.x;
    const int cg = t0 & 3;                  // same for all chunks (CHUNK%4==0)

    // phase 1: flow loads (independent)
    float2 f[NPIX];
    int pix[NPIX];
    #pragma unroll
    for (int i = 0; i < NPIX; ++i) {
        const int u = t0 + i * CHUNK;
        pix[i] = u >> 2;
        f[i] = ((const float2*)flow)[pix[i]];
    }

    // phase 2: address math
    const float* p[NPIX];
    float ay[NPIX], ax[NPIX];
    #pragma unroll
    for (int i = 0; i < NPIX; ++i) {
        const int u = t0 + i * CHUNK;
        const int x = (u >> 2) & 511;
        const int y = (u >> 11) & 511;
        const int b = u >> 20;

        const float qy = (float)y - f[i].x;
        const float qx = (float)x - f[i].y;
        float fy = floorf(qy); fy = fminf(fmaxf(fy, 0.0f), 510.0f);
        float fx = floorf(qx); fx = fminf(fmaxf(fx, 0.0f), 510.0f);
        ay[i] = fminf(fmaxf(qy - fy, 0.0f), 1.0f);
        ax[i] = fminf(fmaxf(qx - fx, 0.0f), 1.0f);
        const int iy = (int)fy;
        const int ix = (int)fx;
        p[i] = img + ((size_t)((((b << 9) + iy) << 9) + ix)) * 16 + (cg << 2);
    }

    // phase 3: all 16 corner gathers (independent, overlap in flight)
    float4 tl[NPIX], tr[NPIX], bl[NPIX], br[NPIX];
    #pragma unroll
    for (int i = 0; i < NPIX; ++i) {
        tl[i] = *(const float4*)(p[i]);
        tr[i] = *(const float4*)(p[i] + 16);
        bl[i] = *(const float4*)(p[i] + 512 * 16);
        br[i] = *(const float4*)(p[i] + 512 * 16 + 16);
    }

    // phase 4: interpolate + store
    #pragma unroll
    for (int i = 0; i < NPIX; ++i) {
        float4 r;
        float t, u;
        t = tl[i].x + ax[i] * (tr[i].x - tl[i].x);
        u = bl[i].x + ax[i] * (br[i].x - bl[i].x);
        r.x = t + ay[i] * (u - t);
        t = tl[i].y + ax[i] * (tr[i].y - tl[i].y);
        u = bl[i].y + ax[i] * (br[i].y - bl[i].y);
        r.y = t + ay[i] * (u - t);
        t = tl[i].z + ax[i] * (tr[i].z - tl[i].z);
        u = bl[i].z + ax[i] * (br[i].z - bl[i].z);
        r.z = t + ay[i] * (u - t);
        t = tl[i].w + ax[i] * (tr[i].w - tl[i].w);
        u = bl[i].w + ax[i] * (br[i].w - bl[i].w);
        r.w = t + ay[i] * (u - t);

        ((float4*)out)[t0 + i * CHUNK] = r;
    }
}

extern "C" void kernel_launch(void* const* d_in, const int* in_sizes, int n_in,
                              void* d_out, int out_size, void* d_ws, size_t ws_size,
                              hipStream_t stream) {
    const float* img  = (const float*)d_in[0];
    const float* flow = (const float*)d_in[1];
    float* out = (float*)d_out;

    const int block = 256;
    const int grid = CHUNK / block;        // 8192 blocks
    warp_kernel<<<grid, block, 0, stream>>>(img, flow, out);
}

// Round 7
// 240.581 us; speedup vs baseline: 1.0395x; 1.0395x over previous
//
#include <hip/hip_runtime.h>

// dense_image_warp: B=8, H=512, W=512, C=16, fp32.
//
// R5: pair-merged gathers. tl|tr (and bl|br) are one contiguous 128B span per
// pixel; previously fetched by separate wave instructions (no cross-instr
// coalescing) -> ~4 line-requests/pixel at the TA. Now one instruction covers
// 8 pixels x 128B top spans (8 lanes/pixel), another the bottom spans:
// expected ~3 line-requests/pixel. VMEM instruction count per thread is
// UNCHANGED (1 flow + 4 gathers + 1 store) -- this isolates the line-count
// variable. Load->compute lane remap via one packed xor-4 ds_swizzle per row.
// R6: resubmit unchanged (R5 bench was an infra failure, kernel never ran).
//
// Lane layout (per wave): lane = 8*q + s, q=0..7 groups, s=0..7 slots.
//   loads:  instr T0 covers top span of pixel (base+q)   slot s -> bytes 16s..
//           instr T1 covers top span of pixel (base+8+q)
//           B0/B1 same for bottom spans (+32768 B).
//   compute: thread owns pixel p = base + q + 8*hi (hi = s>=4), cg = s&3.
//   exchange: partner lane l^4 holds the other half of my spans; one packed
//   swizzle per row delivers it (I send what my partner needs).

__device__ __forceinline__ float swz4(float v) {
    return __int_as_float(__builtin_amdgcn_ds_swizzle(__float_as_int(v), 0x101F)); // xor 4
}
__device__ __forceinline__ float4 swz4(float4 v) {
    float4 r;
    r.x = swz4(v.x); r.y = swz4(v.y); r.z = swz4(v.z); r.w = swz4(v.w);
    return r;
}

__global__ __launch_bounds__(256) void warp_kernel(
    const float* __restrict__ img,
    const float* __restrict__ flow,
    float* __restrict__ out)
{
    const int tid  = blockIdx.x * blockDim.x + threadIdx.x;
    const int lane = threadIdx.x & 63;
    const int s    = lane & 7;
    const int q    = (lane >> 3) & 7;
    const int hi   = (s >> 2) & 1;      // 0: pixel base+q, 1: pixel base+8+q
    const int cg   = s & 3;

    const int pixbase = (tid >> 6) << 4;        // global wave id * 16 pixels
    const int p = pixbase + q + (hi << 3);      // this thread's compute pixel

    const int x = p & 511;
    const int y = (p >> 9) & 511;
    const int b = p >> 18;

    const float2 f = ((const float2*)flow)[p];
    const float qy = (float)y - f.x;
    const float qx = (float)x - f.y;
    float fy = floorf(qy); fy = fminf(fmaxf(fy, 0.0f), 510.0f);
    float fx = floorf(qx); fx = fminf(fmaxf(fx, 0.0f), 510.0f);
    const float ay = fminf(fmaxf(qy - fy, 0.0f), 1.0f);
    const float ax = fminf(fmaxf(qx - fx, 0.0f), 1.0f);
    const int iy = (int)fy;
    const int ix = (int)fx;

    // byte offset of my pixel's top-left 64B segment (max 2^27, fits int)
    const int mytop = ((((b << 9) + iy) << 9) + ix) << 6;
    // partner lane (l^4) owns the other round's pixel; exchange bases
    const int othertop = __builtin_amdgcn_ds_swizzle(mytop, 0x101F);
    const int top0 = hi ? othertop : mytop;     // round-0 pixel's top base
    const int top1 = hi ? mytop    : othertop;  // round-1 pixel's top base

    const char* img8 = (const char*)img;
    const int so = s << 4;                      // slot byte offset 0..112

    const float4 T0 = *(const float4*)(img8 + top0 + so);
    const float4 T1 = *(const float4*)(img8 + top1 + so);
    const float4 B0 = *(const float4*)(img8 + top0 + 32768 + so);
    const float4 B1 = *(const float4*)(img8 + top1 + 32768 + so);

    // redistribute: send the reg my partner needs, receive my missing half
    const float4 sendT = hi ? T0 : T1;
    const float4 sendB = hi ? B0 : B1;
    const float4 recvT = swz4(sendT);
    const float4 recvB = swz4(sendB);

    const float4 tl = hi ? recvT : T0;
    const float4 tr = hi ? T1    : recvT;
    const float4 bl = hi ? recvB : B0;
    const float4 br = hi ? B1    : recvB;

    float4 r;
    {
        float t0, u0;
        t0 = tl.x + ax * (tr.x - tl.x);
        u0 = bl.x + ax * (br.x - bl.x);
        r.x = t0 + ay * (u0 - t0);
        t0 = tl.y + ax * (tr.y - tl.y);
        u0 = bl.y + ax * (br.y - bl.y);
        r.y = t0 + ay * (u0 - t0);
        t0 = tl.z + ax * (tr.z - tl.z);
        u0 = bl.z + ax * (br.z - bl.z);
        r.z = t0 + ay * (u0 - t0);
        t0 = tl.w + ax * (tr.w - tl.w);
        u0 = bl.w + ax * (br.w - bl.w);
        r.w = t0 + ay * (u0 - t0);
    }

    ((float4*)out)[(p << 2) + cg] = r;
}

extern "C" void kernel_launch(void* const* d_in, const int* in_sizes, int n_in,
                              void* d_out, int out_size, void* d_ws, size_t ws_size,
                              hipStream_t stream) {
    const float* img  = (const float*)d_in[0];
    const float* flow = (const float*)d_in[1];
    float* out = (float*)d_out;

    const int total = 8 * 512 * 512 * 4;   // threads (float4 granularity)
    const int block = 256;
    const int grid = total / block;        // 32768
    warp_kernel<<<grid, block, 0, stream>>>(img, flow, out);
}